// Round 1
// baseline (2621.252 us; speedup 1.0000x reference)
//
#include <hip/hip_runtime.h>
#include <hip/hip_bf16.h>
#include <math.h>

#define NN 512   // hidden states
#define MM 256   // timesteps / emission symbols
#define BB 128   // batch

typedef _Float16 half8 __attribute__((ext_vector_type(8)));

// ---------------- wave (64-lane) reductions ----------------
__device__ __forceinline__ float wave_max(float v) {
#pragma unroll
    for (int o = 32; o > 0; o >>= 1) v = fmaxf(v, __shfl_xor(v, o));
    return v;
}
__device__ __forceinline__ float wave_sum(float v) {
#pragma unroll
    for (int o = 32; o > 0; o >>= 1) v += __shfl_xor(v, o);
    return v;
}

// ---------------- preprocessing ----------------

// Column-wise logsumexp of T (log_softmax axis=0 denominator). grid 8 x 64.
__global__ void k_col_lse(const float* __restrict__ T, float* __restrict__ c) {
    int k = blockIdx.x * 64 + threadIdx.x;   // column
    float m = -INFINITY, s = 0.f;
    for (int i = 0; i < NN; ++i) {
        float x = T[i * NN + k];             // coalesced across threads
        if (x > m) { s = s * __expf(m - x) + 1.f; m = x; }
        else       { s += __expf(x - m); }
    }
    c[k] = m + __logf(s);
}

// log-softmax of priors. grid 1 x 512.
__global__ void k_priors(const float* __restrict__ pr, float* __restrict__ lp) {
    __shared__ float red[8];
    int i = threadIdx.x;
    float x = pr[i];
    float wm = wave_max(x);
    if ((i & 63) == 0) red[i >> 6] = wm;
    __syncthreads();
    float m = red[0];
#pragma unroll
    for (int j = 1; j < 8; ++j) m = fmaxf(m, red[j]);
    float e = __expf(x - m);
    float ws = wave_sum(e);
    __syncthreads();
    if ((i & 63) == 0) red[i >> 6] = ws;
    __syncthreads();
    float S = red[0];
#pragma unroll
    for (int j = 1; j < 8; ++j) S += red[j];
    lp[i] = x - (m + __logf(S));
}

// Per-row i of T: mT[i] = max_k(T[i,k]-c[k]); P fp16 in packed layout
// P4[(k>>3)*NN*8 + i*8 + (k&7)] = exp(T[i,k]-c[k]-mT[i]).  grid 512 x 64.
__global__ void k_rowT(const float* __restrict__ T, const float* __restrict__ c,
                       float* __restrict__ mT, _Float16* __restrict__ P4) {
    int i = blockIdx.x, j = threadIdx.x;     // thread j owns k = 8j..8j+7
    float v[8];
    float mx = -INFINITY;
#pragma unroll
    for (int d = 0; d < 8; ++d) {
        int k = j * 8 + d;
        v[d] = T[i * NN + k] - c[k];
        mx = fmaxf(mx, v[d]);
    }
    mx = wave_max(mx);                       // 64 threads == 1 wave
    if (j == 0) mT[i] = mx;
    half8 o;
#pragma unroll
    for (int d = 0; d < 8; ++d) o[d] = (_Float16)__expf(v[d] - mx);
    *(half8*)(P4 + ((size_t)j * NN + i) * 8) = o;
}

// Per-row i of E: row log-softmax, store transposed EtT[m*NN+i]. grid 512 x 64.
__global__ void k_rowE(const float* __restrict__ E, float* __restrict__ EtT) {
    int i = blockIdx.x, j = threadIdx.x;     // thread j owns m = 4j..4j+3
    float v[4];
    float mx = -INFINITY;
#pragma unroll
    for (int d = 0; d < 4; ++d) {
        v[d] = E[i * MM + j * 4 + d];
        mx = fmaxf(mx, v[d]);
    }
    mx = wave_max(mx);
    float s = 0.f;
#pragma unroll
    for (int d = 0; d < 4; ++d) s += __expf(v[d] - mx);
    s = wave_sum(s);
    float lse = mx + __logf(s);
#pragma unroll
    for (int d = 0; d < 4; ++d) EtT[(size_t)(j * 4 + d) * NN + i] = v[d] - lse;
}

// ---------------- the scan ----------------
// One block per batch element, 512 threads (thread i owns state i).
__global__ __launch_bounds__(512, 1) void k_scan(
        const int* __restrict__ obs, const float* __restrict__ lp,
        const float* __restrict__ mT, const _Float16* __restrict__ P4,
        const float* __restrict__ EtT, float* __restrict__ out) {
    int b = blockIdx.x, i = threadIdx.x;
    __shared__ _Float16 u16[NN] __attribute__((aligned(16)));
    __shared__ float rA[8], rB[8];
    __shared__ int obs_s[MM];
    if (i < MM) obs_s[i] = obs[b * MM + i];
    float mTi = mT[i];
    float lpi = lp[i];
    __syncthreads();

    const half8* Pv = (const half8*)P4;      // Pv[(k8<<9)+i] = 8 fp16 for state i, k-octet k8
    const half8* Uv = (const half8*)u16;

    float m = 0.f;                           // running shift (max of a_prev)
    float a = 0.f;

    for (int t = 0; t < MM; ++t) {
        int o = obs_s[t];
        if (t == 0) {
            a = EtT[(size_t)o * NN + i] + lpi;
        } else {
            float s0 = 0.f, s1 = 0.f, s2 = 0.f, s3 = 0.f;
#pragma unroll 16
            for (int k8 = 0; k8 < 64; ++k8) {
                half8 p  = Pv[(k8 << 9) + i];    // 16B coalesced global (L2-hot)
                half8 uu = Uv[k8];               // 16B LDS broadcast
                s0 = fmaf((float)p[0], (float)uu[0], s0);
                s1 = fmaf((float)p[1], (float)uu[1], s1);
                s2 = fmaf((float)p[2], (float)uu[2], s2);
                s3 = fmaf((float)p[3], (float)uu[3], s3);
                s0 = fmaf((float)p[4], (float)uu[4], s0);
                s1 = fmaf((float)p[5], (float)uu[5], s1);
                s2 = fmaf((float)p[6], (float)uu[6], s2);
                s3 = fmaf((float)p[7], (float)uu[7], s3);
            }
            float s = (s0 + s1) + (s2 + s3);
            a = EtT[(size_t)o * NN + i] + mTi + m + __logf(s);
        }
        // block max of a
        float wm = wave_max(a);
        __syncthreads();                     // S1: all u16 reads of this iter done
        if ((i & 63) == 0) rA[i >> 6] = wm;
        __syncthreads();                     // S2: rA ready
        float mn = rA[0];
#pragma unroll
        for (int j = 1; j < 8; ++j) mn = fmaxf(mn, rA[j]);
        float e = __expf(a - mn);
        float ws = wave_sum(e);
        if ((i & 63) == 0) rB[i >> 6] = ws;
        u16[i] = (_Float16)e;                // safe: reads completed at S1
        __syncthreads();                     // S3: rB + u16 ready
        if (i == 0) {
            float S = rB[0];
#pragma unroll
            for (int j = 1; j < 8; ++j) S += rB[j];
            out[(size_t)b * MM + t] = mn + __logf(S);
        }
        m = mn;
    }
}

extern "C" void kernel_launch(void* const* d_in, const int* in_sizes, int n_in,
                              void* d_out, int out_size, void* d_ws, size_t ws_size,
                              hipStream_t stream) {
    const int*   obs = (const int*)d_in[0];
    const float* pri = (const float*)d_in[1];
    const float* T   = (const float*)d_in[2];
    const float* E   = (const float*)d_in[3];
    float* out = (float*)d_out;
    char* ws = (char*)d_ws;

    float*    c   = (float*)(ws + 0);
    float*    lp  = (float*)(ws + 2048);
    float*    mT  = (float*)(ws + 4096);
    _Float16* P4  = (_Float16*)(ws + 8192);                 // 512KB
    float*    EtT = (float*)(ws + 8192 + 512 * 1024);       // 512KB

    k_col_lse<<<8,   64, 0, stream>>>(T, c);
    k_priors <<<1,  512, 0, stream>>>(pri, lp);
    k_rowT   <<<512, 64, 0, stream>>>(T, c, mT, P4);
    k_rowE   <<<512, 64, 0, stream>>>(E, EtT);
    k_scan   <<<BB, 512, 0, stream>>>(obs, lp, mT, P4, EtT, out);
}

// Round 2
// 869.139 us; speedup vs baseline: 3.0159x; 3.0159x over previous
//
#include <hip/hip_runtime.h>
#include <hip/hip_bf16.h>
#include <math.h>

#define NN 512   // hidden states
#define MM 256   // timesteps / emission symbols
#define BB 128   // batch

typedef float        f32x2 __attribute__((ext_vector_type(2)));
typedef float        f32x4 __attribute__((ext_vector_type(4)));
typedef unsigned int u32;
typedef u32          u32x2 __attribute__((ext_vector_type(2)));
typedef u32          u32x4 __attribute__((ext_vector_type(4)));

__device__ __forceinline__ float wave_max(float v) {
#pragma unroll
    for (int o = 32; o > 0; o >>= 1) v = fmaxf(v, __shfl_xor(v, o));
    return v;
}
__device__ __forceinline__ float wave_sum(float v) {
#pragma unroll
    for (int o = 32; o > 0; o >>= 1) v += __shfl_xor(v, o);
    return v;
}
__device__ __forceinline__ f32x2 lo2(f32x4 v) { return __builtin_shufflevector(v, v, 0, 1); }
__device__ __forceinline__ f32x2 hi2(f32x4 v) { return __builtin_shufflevector(v, v, 2, 3); }

// ---------------- preprocessing ----------------

// Column-wise logsumexp of T (log_softmax axis=0 denominator). grid 8 x 64.
__global__ void k_col_lse(const float* __restrict__ T, float* __restrict__ c) {
    int k = blockIdx.x * 64 + threadIdx.x;
    float m = -INFINITY, s = 0.f;
    for (int i = 0; i < NN; ++i) {
        float x = T[i * NN + k];
        if (x > m) { s = s * __expf(m - x) + 1.f; m = x; }
        else       { s += __expf(x - m); }
    }
    c[k] = m + __logf(s);
}

// log-softmax of priors. grid 1 x 512.
__global__ void k_priors(const float* __restrict__ pr, float* __restrict__ lp) {
    __shared__ float red[8];
    int i = threadIdx.x;
    float x = pr[i];
    float wm = wave_max(x);
    if ((i & 63) == 0) red[i >> 6] = wm;
    __syncthreads();
    float m = red[0];
#pragma unroll
    for (int j = 1; j < 8; ++j) m = fmaxf(m, red[j]);
    float e = __expf(x - m);
    float ws = wave_sum(e);
    __syncthreads();
    if ((i & 63) == 0) red[i >> 6] = ws;
    __syncthreads();
    float S = red[0];
#pragma unroll
    for (int j = 1; j < 8; ++j) S += red[j];
    lp[i] = x - (m + __logf(S));
}

// Row i of T: M[i] = max_k(T[i,k]-c[k]) - log(64); P stored fp8(e4m3) scaled x64.
// Layout (u32 dwords): Pq[( (k>>4)*NN + i )*4 + ((k>>2)&3)], bytes = ascending k.
// grid 512 x 64; thread j owns k = 8j..8j+7 -> dwords (j>>1)*... see below.
__global__ void k_rowT(const float* __restrict__ T, const float* __restrict__ c,
                       float* __restrict__ M, u32* __restrict__ Pq) {
    int i = blockIdx.x, j = threadIdx.x;
    float v[8];
    float mx = -INFINITY;
#pragma unroll
    for (int d = 0; d < 8; ++d) {
        int k = j * 8 + d;
        v[d] = T[i * NN + k] - c[k];
        mx = fmaxf(mx, v[d]);
    }
    mx = wave_max(mx);
    if (j == 0) M[i] = mx - __logf(64.f);
    float p[8];
#pragma unroll
    for (int d = 0; d < 8; ++d) p[d] = __expf(v[d] - mx) * 64.f;
    int d0 = 0, d1 = 0;
    d0 = __builtin_amdgcn_cvt_pk_fp8_f32(p[0], p[1], d0, false);
    d0 = __builtin_amdgcn_cvt_pk_fp8_f32(p[2], p[3], d0, true);
    d1 = __builtin_amdgcn_cvt_pk_fp8_f32(p[4], p[5], d1, false);
    d1 = __builtin_amdgcn_cvt_pk_fp8_f32(p[6], p[7], d1, true);
    u32x2 st = { (u32)d0, (u32)d1 };
    // dword group j4 = j>>1 holds k = 16*j4 .. 16*j4+15; this thread's 2 dwords:
    *(u32x2*)(Pq + ((size_t)(j >> 1) * NN + i) * 4 + (j & 1) * 2) = st;
}

// Row i of E: log-softmax, store transposed EtT[m*NN+i]. grid 512 x 64.
__global__ void k_rowE(const float* __restrict__ E, float* __restrict__ EtT) {
    int i = blockIdx.x, j = threadIdx.x;
    float v[4];
    float mx = -INFINITY;
#pragma unroll
    for (int d = 0; d < 4; ++d) {
        v[d] = E[i * MM + j * 4 + d];
        mx = fmaxf(mx, v[d]);
    }
    mx = wave_max(mx);
    float s = 0.f;
#pragma unroll
    for (int d = 0; d < 4; ++d) s += __expf(v[d] - mx);
    s = wave_sum(s);
    float lse = mx + __logf(s);
#pragma unroll
    for (int d = 0; d < 4; ++d) EtT[(size_t)(j * 4 + d) * NN + i] = v[d] - lse;
}

// ---------------- the scan ----------------
// One block per batch, 512 threads (thread i owns state i).
// P row lives in 128 VGPRs as fp8; u (softmax of alpha) lives in LDS as f32.
__global__ __launch_bounds__(512, 2) void k_scan(
        const int* __restrict__ obs, const float* __restrict__ lp,
        const float* __restrict__ M, const u32* __restrict__ Pq,
        const float* __restrict__ EtT, float* __restrict__ out) {
    int b = blockIdx.x, i = threadIdx.x;
    __shared__ float us[NN] __attribute__((aligned(16)));
    __shared__ float rA[8];   // startup C reduction
    __shared__ float rB[8];   // per-step sum reduction
    __shared__ int obs_s[MM];
    if (i < MM) obs_s[i] = obs[b * MM + i];
    float Mi  = M[i];
    float lpi = lp[i];

    // C = max_i mT[i] = max_i M[i] + log(64)
    float wm = wave_max(Mi);
    if ((i & 63) == 0) rA[i >> 6] = wm;

    // load P row into registers: 32 x uint4 (128 fp8-dwords)
    u32x4 preg[32];
    const u32x4* Pq4 = (const u32x4*)Pq;
#pragma unroll
    for (int j4 = 0; j4 < 32; ++j4) preg[j4] = Pq4[(size_t)j4 * NN + i];

    __syncthreads();
    float C = rA[0];
#pragma unroll
    for (int j = 1; j < 8; ++j) C = fmaxf(C, rA[j]);
    C += __logf(64.f);

    const f32x4* Us4 = (const f32x4*)us;
    float L = 0.f;
    float emv = EtT[(size_t)obs_s[0] * NN + i];

#pragma unroll 1
    for (int t = 0; t < MM; ++t) {
        float em_n = (t + 1 < MM) ? EtT[(size_t)obs_s[t + 1] * NN + i] : 0.f;
        float g;
        if (t == 0) {
            g = emv + lpi;                   // alpha_0 (<= 0), shift C0 = 0
        } else {
            f32x2 a0 = {0.f,0.f}, a1 = {0.f,0.f}, a2 = {0.f,0.f}, a3 = {0.f,0.f};
            f32x2 a4 = {0.f,0.f}, a5 = {0.f,0.f}, a6 = {0.f,0.f}, a7 = {0.f,0.f};
#pragma unroll
            for (int j4 = 0; j4 < 32; ++j4) {
                u32x4 w = preg[j4];
                f32x4 u0 = Us4[4 * j4 + 0];
                a0 += __builtin_amdgcn_cvt_pk_f32_fp8((int)w.x, false) * lo2(u0);
                a1 += __builtin_amdgcn_cvt_pk_f32_fp8((int)w.x, true)  * hi2(u0);
                f32x4 u1 = Us4[4 * j4 + 1];
                a2 += __builtin_amdgcn_cvt_pk_f32_fp8((int)w.y, false) * lo2(u1);
                a3 += __builtin_amdgcn_cvt_pk_f32_fp8((int)w.y, true)  * hi2(u1);
                f32x4 u2 = Us4[4 * j4 + 2];
                a4 += __builtin_amdgcn_cvt_pk_f32_fp8((int)w.z, false) * lo2(u2);
                a5 += __builtin_amdgcn_cvt_pk_f32_fp8((int)w.z, true)  * hi2(u2);
                f32x4 u3 = Us4[4 * j4 + 3];
                a6 += __builtin_amdgcn_cvt_pk_f32_fp8((int)w.w, false) * lo2(u3);
                a7 += __builtin_amdgcn_cvt_pk_f32_fp8((int)w.w, true)  * hi2(u3);
            }
            f32x2 a01 = a0 + a1, a23 = a2 + a3, a45 = a4 + a5, a67 = a6 + a7;
            f32x2 aa = (a01 + a23) + (a45 + a67);
            float s = aa.x + aa.y;           // = 64 * sum_k P[i,k] u[k]
            g = emv + Mi + __logf(s);        // Mi folds the /64
        }
        float Ct = (t == 0) ? 0.f : C;
        float e = __expf(g - Ct);            // <= 1 by construction
        float ws = wave_sum(e);
        if ((i & 63) == 0) rB[i >> 6] = ws;
        __syncthreads();                     // A: dots done + rB ready
        float S = rB[0];
#pragma unroll
        for (int j = 1; j < 8; ++j) S += rB[j];
        us[i] = e * (1.0f / S);              // u = softmax(alpha), sums to 1
        L += Ct + __logf(S);
        if (i == 0) out[(size_t)b * MM + t] = L;
        emv = em_n;
        __syncthreads();                     // B: us ready for next step
    }
}

extern "C" void kernel_launch(void* const* d_in, const int* in_sizes, int n_in,
                              void* d_out, int out_size, void* d_ws, size_t ws_size,
                              hipStream_t stream) {
    const int*   obs = (const int*)d_in[0];
    const float* pri = (const float*)d_in[1];
    const float* T   = (const float*)d_in[2];
    const float* E   = (const float*)d_in[3];
    float* out = (float*)d_out;
    char* ws = (char*)d_ws;

    float* c   = (float*)(ws + 0);
    float* lp  = (float*)(ws + 2048);
    float* M   = (float*)(ws + 4096);
    u32*   Pq  = (u32*)(ws + 8192);                       // 256 KB fp8
    float* EtT = (float*)(ws + 8192 + 256 * 1024);        // 512 KB

    k_col_lse<<<8,   64, 0, stream>>>(T, c);
    k_priors <<<1,  512, 0, stream>>>(pri, lp);
    k_rowT   <<<512, 64, 0, stream>>>(T, c, M, Pq);
    k_rowE   <<<512, 64, 0, stream>>>(E, EtT);
    k_scan   <<<BB, 512, 0, stream>>>(obs, lp, M, Pq, EtT, out);
}

// Round 3
// 857.381 us; speedup vs baseline: 3.0573x; 1.0137x over previous
//
#include <hip/hip_runtime.h>
#include <hip/hip_bf16.h>
#include <math.h>

#define NN 512   // hidden states
#define MM 256   // timesteps / emission symbols
#define BB 128   // batch

typedef float        f32x2 __attribute__((ext_vector_type(2)));
typedef float        f32x4 __attribute__((ext_vector_type(4)));
typedef unsigned int u32;
typedef u32          u32x2 __attribute__((ext_vector_type(2)));
typedef u32          u32x4 __attribute__((ext_vector_type(4)));

__device__ __forceinline__ float wave_max(float v) {
#pragma unroll
    for (int o = 32; o > 0; o >>= 1) v = fmaxf(v, __shfl_xor(v, o));
    return v;
}
__device__ __forceinline__ float wave_sum(float v) {
#pragma unroll
    for (int o = 32; o > 0; o >>= 1) v += __shfl_xor(v, o);
    return v;
}
__device__ __forceinline__ f32x2 lo2(f32x4 v) { return __builtin_shufflevector(v, v, 0, 1); }
__device__ __forceinline__ f32x2 hi2(f32x4 v) { return __builtin_shufflevector(v, v, 2, 3); }

// ---------------- preprocessing ----------------

// Column-wise logsumexp of T (log_softmax axis=0 denominator). grid 8 x 64.
__global__ void k_col_lse(const float* __restrict__ T, float* __restrict__ c) {
    int k = blockIdx.x * 64 + threadIdx.x;
    float m = -INFINITY, s = 0.f;
    for (int i = 0; i < NN; ++i) {
        float x = T[i * NN + k];
        if (x > m) { s = s * __expf(m - x) + 1.f; m = x; }
        else       { s += __expf(x - m); }
    }
    c[k] = m + __logf(s);
}

// log-softmax of priors. grid 1 x 512.
__global__ void k_priors(const float* __restrict__ pr, float* __restrict__ lp) {
    __shared__ float red[8];
    int i = threadIdx.x;
    float x = pr[i];
    float wm = wave_max(x);
    if ((i & 63) == 0) red[i >> 6] = wm;
    __syncthreads();
    float m = red[0];
#pragma unroll
    for (int j = 1; j < 8; ++j) m = fmaxf(m, red[j]);
    float e = __expf(x - m);
    float ws = wave_sum(e);
    __syncthreads();
    if ((i & 63) == 0) red[i >> 6] = ws;
    __syncthreads();
    float S = red[0];
#pragma unroll
    for (int j = 1; j < 8; ++j) S += red[j];
    lp[i] = x - (m + __logf(S));
}

// Row i of T: M[i] = max_k(T[i,k]-c[k]) - log(64); P stored fp8(e4m3) scaled x64.
// Layout (u32 dwords): Pq[( (k>>4)*NN + i )*4 + ((k>>2)&3)], bytes = ascending k.
__global__ void k_rowT(const float* __restrict__ T, const float* __restrict__ c,
                       float* __restrict__ M, u32* __restrict__ Pq) {
    int i = blockIdx.x, j = threadIdx.x;
    float v[8];
    float mx = -INFINITY;
#pragma unroll
    for (int d = 0; d < 8; ++d) {
        int k = j * 8 + d;
        v[d] = T[i * NN + k] - c[k];
        mx = fmaxf(mx, v[d]);
    }
    mx = wave_max(mx);
    if (j == 0) M[i] = mx - __logf(64.f);
    float p[8];
#pragma unroll
    for (int d = 0; d < 8; ++d) p[d] = __expf(v[d] - mx) * 64.f;
    int d0 = 0, d1 = 0;
    d0 = __builtin_amdgcn_cvt_pk_fp8_f32(p[0], p[1], d0, false);
    d0 = __builtin_amdgcn_cvt_pk_fp8_f32(p[2], p[3], d0, true);
    d1 = __builtin_amdgcn_cvt_pk_fp8_f32(p[4], p[5], d1, false);
    d1 = __builtin_amdgcn_cvt_pk_fp8_f32(p[6], p[7], d1, true);
    u32x2 st = { (u32)d0, (u32)d1 };
    *(u32x2*)(Pq + ((size_t)(j >> 1) * NN + i) * 4 + (j & 1) * 2) = st;
}

// Row i of E: log-softmax, store transposed EtT[m*NN+i]. grid 512 x 64.
__global__ void k_rowE(const float* __restrict__ E, float* __restrict__ EtT) {
    int i = blockIdx.x, j = threadIdx.x;
    float v[4];
    float mx = -INFINITY;
#pragma unroll
    for (int d = 0; d < 4; ++d) {
        v[d] = E[i * MM + j * 4 + d];
        mx = fmaxf(mx, v[d]);
    }
    mx = wave_max(mx);
    float s = 0.f;
#pragma unroll
    for (int d = 0; d < 4; ++d) s += __expf(v[d] - mx);
    s = wave_sum(s);
    float lse = mx + __logf(s);
#pragma unroll
    for (int d = 0; d < 4; ++d) EtT[(size_t)(j * 4 + d) * NN + i] = v[d] - lse;
}

// ---------------- the scan ----------------
// One block per batch, 512 threads (thread i owns state i).
// P row pinned in 128 VGPRs (fp8); unnormalized e in double-buffered LDS;
// one barrier per step (normalization deferred via lS_prev).
__global__ __launch_bounds__(512, 2) void k_scan(
        const int* __restrict__ obs, const float* __restrict__ lp,
        const float* __restrict__ M, const u32* __restrict__ Pq,
        const float* __restrict__ EtT, float* __restrict__ out) {
    int b = blockIdx.x, i = threadIdx.x;
    __shared__ float us[2][NN] __attribute__((aligned(16)));
    __shared__ float rA[8];
    __shared__ float rB[2][8];
    __shared__ int obs_s[MM];
    if (i < MM) obs_s[i] = obs[b * MM + i];
    float Mi  = M[i];
    float lpi = lp[i];

    float wm = wave_max(Mi);
    if ((i & 63) == 0) rA[i >> 6] = wm;

    // load P row into registers: 32 x uint4 = 128 dwords of fp8
    u32x4 preg[32];
    const u32x4* Pq4 = (const u32x4*)Pq;
#pragma unroll
    for (int j4 = 0; j4 < 32; ++j4) preg[j4] = Pq4[(size_t)j4 * NN + i];
    // Pin: opaque asm may "modify" the regs -> compiler cannot re-load from
    // memory inside the loop; P stays VGPR-resident for all 256 steps.
#pragma unroll
    for (int j4 = 0; j4 < 32; ++j4) asm volatile("" : "+v"(preg[j4]));

    __syncthreads();
    float C = rA[0];
#pragma unroll
    for (int j = 1; j < 8; ++j) C = fmaxf(C, rA[j]);
    C += __logf(64.f);

    float L = 0.f;
    float lSp = 0.f;                         // log of previous step's sum S
    float emv = EtT[(size_t)obs_s[0] * NN + i];
    int cur = 0;

#pragma unroll 1
    for (int t = 0; t < MM; ++t) {
        float em_n = (t + 1 < MM) ? EtT[(size_t)obs_s[t + 1] * NN + i] : 0.f;
        float g;
        if (t == 0) {
            g = emv + lpi;                   // alpha_0 (<= 0), shift 0
        } else {
            const f32x4* Us4 = (const f32x4*)us[cur];
            f32x2 a0 = {0.f,0.f}, a1 = {0.f,0.f}, a2 = {0.f,0.f}, a3 = {0.f,0.f};
            f32x2 a4 = {0.f,0.f}, a5 = {0.f,0.f}, a6 = {0.f,0.f}, a7 = {0.f,0.f};
#pragma unroll
            for (int j4 = 0; j4 < 32; ++j4) {
                u32x4 w = preg[j4];
                f32x4 u0 = Us4[4 * j4 + 0];
                a0 += __builtin_amdgcn_cvt_pk_f32_fp8((int)w.x, false) * lo2(u0);
                a1 += __builtin_amdgcn_cvt_pk_f32_fp8((int)w.x, true)  * hi2(u0);
                f32x4 u1 = Us4[4 * j4 + 1];
                a2 += __builtin_amdgcn_cvt_pk_f32_fp8((int)w.y, false) * lo2(u1);
                a3 += __builtin_amdgcn_cvt_pk_f32_fp8((int)w.y, true)  * hi2(u1);
                f32x4 u2 = Us4[4 * j4 + 2];
                a4 += __builtin_amdgcn_cvt_pk_f32_fp8((int)w.z, false) * lo2(u2);
                a5 += __builtin_amdgcn_cvt_pk_f32_fp8((int)w.z, true)  * hi2(u2);
                f32x4 u3 = Us4[4 * j4 + 3];
                a6 += __builtin_amdgcn_cvt_pk_f32_fp8((int)w.w, false) * lo2(u3);
                a7 += __builtin_amdgcn_cvt_pk_f32_fp8((int)w.w, true)  * hi2(u3);
            }
            f32x2 a01 = a0 + a1, a23 = a2 + a3, a45 = a4 + a5, a67 = a6 + a7;
            f32x2 aa = (a01 + a23) + (a45 + a67);
            float s = aa.x + aa.y;           // = 64 * S_prev * sum_k P u_hat
            g = emv + Mi + __logf(s) - lSp;  // Mi folds the /64
        }
        float Ct = (t == 0) ? 0.f : C;
        float e = __expf(g - Ct);            // <= 1 by construction
        int nxt = cur ^ 1;
        us[nxt][i] = e;                      // unnormalized; no WAR on us[cur]
        float ws = wave_sum(e);
        if ((i & 63) == 0) rB[nxt][i >> 6] = ws;
        __syncthreads();                     // the ONLY barrier per step
        float S = rB[nxt][0];
#pragma unroll
        for (int j = 1; j < 8; ++j) S += rB[nxt][j];
        lSp = __logf(S);
        L += Ct + lSp;
        if (i == 0) out[(size_t)b * MM + t] = L;
        emv = em_n;
        cur = nxt;
    }
}

extern "C" void kernel_launch(void* const* d_in, const int* in_sizes, int n_in,
                              void* d_out, int out_size, void* d_ws, size_t ws_size,
                              hipStream_t stream) {
    const int*   obs = (const int*)d_in[0];
    const float* pri = (const float*)d_in[1];
    const float* T   = (const float*)d_in[2];
    const float* E   = (const float*)d_in[3];
    float* out = (float*)d_out;
    char* ws = (char*)d_ws;

    float* c   = (float*)(ws + 0);
    float* lp  = (float*)(ws + 2048);
    float* M   = (float*)(ws + 4096);
    u32*   Pq  = (u32*)(ws + 8192);                       // 256 KB fp8
    float* EtT = (float*)(ws + 8192 + 256 * 1024);        // 512 KB

    k_col_lse<<<8,   64, 0, stream>>>(T, c);
    k_priors <<<1,  512, 0, stream>>>(pri, lp);
    k_rowT   <<<512, 64, 0, stream>>>(T, c, M, Pq);
    k_rowE   <<<512, 64, 0, stream>>>(E, EtT);
    k_scan   <<<BB, 512, 0, stream>>>(obs, lp, M, Pq, EtT, out);
}

// Round 4
// 739.767 us; speedup vs baseline: 3.5434x; 1.1590x over previous
//
#include <hip/hip_runtime.h>
#include <hip/hip_bf16.h>
#include <math.h>

#define NN 512   // hidden states
#define MM 256   // timesteps / emission symbols
#define BB 128   // batch

typedef float        f32x4 __attribute__((ext_vector_type(4)));
typedef unsigned int u32;
typedef u32          u32x2 __attribute__((ext_vector_type(2)));
typedef unsigned long long u64;

__device__ __forceinline__ float wave_max(float v) {
#pragma unroll
    for (int o = 32; o > 0; o >>= 1) v = fmaxf(v, __shfl_xor(v, o));
    return v;
}
__device__ __forceinline__ float wave_sum(float v) {
#pragma unroll
    for (int o = 32; o > 0; o >>= 1) v += __shfl_xor(v, o);
    return v;
}

// ---------------- preprocessing ----------------

// Column-wise logsumexp of T (log_softmax axis=0 denominator). grid 8 x 64.
__global__ void k_col_lse(const float* __restrict__ T, float* __restrict__ c) {
    int k = blockIdx.x * 64 + threadIdx.x;
    float m = -INFINITY, s = 0.f;
    for (int i = 0; i < NN; ++i) {
        float x = T[i * NN + k];
        if (x > m) { s = s * __expf(m - x) + 1.f; m = x; }
        else       { s += __expf(x - m); }
    }
    c[k] = m + __logf(s);
}

// log-softmax of priors. grid 1 x 512.
__global__ void k_priors(const float* __restrict__ pr, float* __restrict__ lp) {
    __shared__ float red[8];
    int i = threadIdx.x;
    float x = pr[i];
    float wm = wave_max(x);
    if ((i & 63) == 0) red[i >> 6] = wm;
    __syncthreads();
    float m = red[0];
#pragma unroll
    for (int j = 1; j < 8; ++j) m = fmaxf(m, red[j]);
    float e = __expf(x - m);
    float ws = wave_sum(e);
    __syncthreads();
    if ((i & 63) == 0) red[i >> 6] = ws;
    __syncthreads();
    float S = red[0];
#pragma unroll
    for (int j = 1; j < 8; ++j) S += red[j];
    lp[i] = x - (m + __logf(S));
}

// Row max: M[i] = max_k(T[i,k]-c[k]) - log(64). grid 512 x 64.
__global__ void k_rowM(const float* __restrict__ T, const float* __restrict__ c,
                       float* __restrict__ M) {
    int i = blockIdx.x, j = threadIdx.x;
    float mx = -INFINITY;
#pragma unroll
    for (int d = 0; d < 8; ++d) {
        int k = j * 8 + d;
        mx = fmaxf(mx, T[i * NN + k] - c[k]);
    }
    mx = wave_max(mx);
    if (j == 0) M[i] = mx - __logf(64.f);
}

// Pack P into fp8 MFMA A-fragments, scaled x64 (row max -> 64).
// Fragment (tile,kc): lane l holds 8 bytes = P[row=tile*16+(l&15),
// k=kc*32+(l>>4)*8+j], j ascending. Stored as u64 at PA8[(tile*16+kc)*64+l].
// grid 512 (=tile*16+kc) x 64.
__global__ void k_packA(const float* __restrict__ T, const float* __restrict__ c,
                        const float* __restrict__ M, u32* __restrict__ PA) {
    int blk = blockIdx.x, l = threadIdx.x;
    int tile = blk >> 4, kc = blk & 15;
    int row = tile * 16 + (l & 15);
    int kb  = kc * 32 + (l >> 4) * 8;
    float Mi = M[row];                    // = rowmax - log64
    float p[8];
#pragma unroll
    for (int j = 0; j < 8; ++j)
        p[j] = __expf(T[row * NN + kb + j] - c[kb + j] - Mi);   // <= 64
    int d0 = 0, d1 = 0;
    d0 = __builtin_amdgcn_cvt_pk_fp8_f32(p[0], p[1], d0, false);
    d0 = __builtin_amdgcn_cvt_pk_fp8_f32(p[2], p[3], d0, true);
    d1 = __builtin_amdgcn_cvt_pk_fp8_f32(p[4], p[5], d1, false);
    d1 = __builtin_amdgcn_cvt_pk_fp8_f32(p[6], p[7], d1, true);
    u32x2 st = { (u32)d0, (u32)d1 };
    *(u32x2*)(PA + ((size_t)blk * 64 + l) * 2) = st;
}

// Row i of E: log-softmax, store transposed EtT[m*NN+i]. grid 512 x 64.
__global__ void k_rowE(const float* __restrict__ E, float* __restrict__ EtT) {
    int i = blockIdx.x, j = threadIdx.x;
    float v[4];
    float mx = -INFINITY;
#pragma unroll
    for (int d = 0; d < 4; ++d) {
        v[d] = E[i * MM + j * 4 + d];
        mx = fmaxf(mx, v[d]);
    }
    mx = wave_max(mx);
    float s = 0.f;
#pragma unroll
    for (int d = 0; d < 4; ++d) s += __expf(v[d] - mx);
    s = wave_sum(s);
    float lse = mx + __logf(s);
#pragma unroll
    for (int d = 0; d < 4; ++d) EtT[(size_t)(j * 4 + d) * NN + i] = v[d] - lse;
}

// ---------------- the scan (MFMA) ----------------
// One block per batch, 512 threads = 8 waves. Wave w owns i-tiles w*4..w*4+3.
// P fp8 A-frags pinned in 128 VGPRs/lane. u (fp8, 512B) in LDS; B = u * ones^T
// (all 16 cols identical), so every lane's C-regs hold valid rows and the
// result is k-permutation invariant (A and B packed with the same lane-map).
__global__ __launch_bounds__(512, 2) void k_scan(
        const int* __restrict__ obs, const float* __restrict__ lp,
        const float* __restrict__ M, const u32* __restrict__ PAu,
        const float* __restrict__ EtT, float* __restrict__ out) {
    int b = blockIdx.x, tid = threadIdx.x;
    int w = tid >> 6, l = tid & 63;
    int hi16 = l >> 4;                    // 0..3
    int r4 = hi16 * 4;                    // row group within a 16-row tile
    __shared__ unsigned char us8[2][NN] __attribute__((aligned(8)));
    __shared__ float rA[8], rB[8];
    __shared__ int obs_s[MM];
    if (tid < MM) obs_s[tid] = obs[b * MM + tid];

    // --- stage A-fragments: 64 x u64 per lane (4 tiles x 16 k-chunks) ---
    const u64* PA8 = (const u64*)PAu;
    u64 pa[64];
#pragma unroll
    for (int ti = 0; ti < 4; ++ti)
#pragma unroll
        for (int kc = 0; kc < 16; ++kc)
            pa[ti * 16 + kc] = PA8[(size_t)(((w * 4 + ti) * 16 + kc)) * 64 + l];
#pragma unroll
    for (int q = 0; q < 64; ++q) asm volatile("" : "+v"(pa[q]));

    // --- per-lane constants in C/D layout: rows (w*4+ti)*16 + r4 + r ---
    f32x4 Mi[4], emv[4], emn[4];
#pragma unroll
    for (int ti = 0; ti < 4; ++ti)
        Mi[ti] = *(const f32x4*)(M + (w * 4 + ti) * 16 + r4);

    __syncthreads();                      // obs_s ready
    int o0 = obs_s[0];
#pragma unroll
    for (int ti = 0; ti < 4; ++ti) {
        f32x4 lpv = *(const f32x4*)(lp + (w * 4 + ti) * 16 + r4);
        emv[ti] = *(const f32x4*)(EtT + (size_t)o0 * NN + (w * 4 + ti) * 16 + r4)
                + lpv;                    // t=0: g = em0 + log_priors
    }

    float L = 0.f;
    int cur = 0;

#pragma unroll 1
    for (int t = 0; t < MM; ++t) {
        // prefetch next emission row (independent of u)
        if (t + 1 < MM) {
            int on = obs_s[t + 1];
#pragma unroll
            for (int ti = 0; ti < 4; ++ti)
                emn[ti] = *(const f32x4*)(EtT + (size_t)on * NN + (w * 4 + ti) * 16 + r4);
        }

        f32x4 g[4];
        if (t == 0) {
#pragma unroll
            for (int ti = 0; ti < 4; ++ti) g[ti] = emv[ti];
        } else {
            f32x4 acc0 = {0.f,0.f,0.f,0.f}, acc1 = {0.f,0.f,0.f,0.f};
            f32x4 acc2 = {0.f,0.f,0.f,0.f}, acc3 = {0.f,0.f,0.f,0.f};
            const unsigned char* ub = us8[cur];
#pragma unroll
            for (int kc = 0; kc < 16; ++kc) {
                u64 bb = *(const u64*)(ub + kc * 32 + hi16 * 8);  // ds_read_b64 broadcast
                acc0 = __builtin_amdgcn_mfma_f32_16x16x32_fp8_fp8((long)pa[0*16+kc], (long)bb, acc0, 0, 0, 0);
                acc1 = __builtin_amdgcn_mfma_f32_16x16x32_fp8_fp8((long)pa[1*16+kc], (long)bb, acc1, 0, 0, 0);
                acc2 = __builtin_amdgcn_mfma_f32_16x16x32_fp8_fp8((long)pa[2*16+kc], (long)bb, acc2, 0, 0, 0);
                acc3 = __builtin_amdgcn_mfma_f32_16x16x32_fp8_fp8((long)pa[3*16+kc], (long)bb, acc3, 0, 0, 0);
            }
            f32x4 sacc[4] = { acc0, acc1, acc2, acc3 };
#pragma unroll
            for (int ti = 0; ti < 4; ++ti)
#pragma unroll
                for (int r = 0; r < 4; ++r)
                    g[ti][r] = emv[ti][r] + Mi[ti][r] + __logf(sacc[ti][r]);
        }

        // --- per-step exact max (keeps fp8 u centered: max e == 1) ---
        float mx = -INFINITY;
#pragma unroll
        for (int ti = 0; ti < 4; ++ti)
#pragma unroll
            for (int r = 0; r < 4; ++r) mx = fmaxf(mx, g[ti][r]);
        mx = wave_max(mx);
        if (l == 0) rA[w] = mx;
        __syncthreads();                  // B1
        float mxt = rA[0];
#pragma unroll
        for (int j = 1; j < 8; ++j) mxt = fmaxf(mxt, rA[j]);

        int nxt = cur ^ 1;
        f32x4 ev[4];
        float loc = 0.f;
#pragma unroll
        for (int ti = 0; ti < 4; ++ti) {
#pragma unroll
            for (int r = 0; r < 4; ++r) {
                float e = __expf(g[ti][r] - mxt);   // <= 1
                ev[ti][r] = e;
                loc += e;
            }
        }
        float ws = wave_sum(loc);         // 16x duplicated across cols
        if (l == 0) rB[w] = ws;
        if ((l & 15) == 0) {              // cols duplicate -> one writer per row-group
#pragma unroll
            for (int ti = 0; ti < 4; ++ti) {
                int d = 0;
                d = __builtin_amdgcn_cvt_pk_fp8_f32(ev[ti][0], ev[ti][1], d, false);
                d = __builtin_amdgcn_cvt_pk_fp8_f32(ev[ti][2], ev[ti][3], d, true);
                *(u32*)&us8[nxt][(w * 4 + ti) * 16 + r4] = (u32)d;
            }
        }
        __syncthreads();                  // B2: rB + us8[nxt] ready
        float S = rB[0];
#pragma unroll
        for (int j = 1; j < 8; ++j) S += rB[j];
        S *= (1.f / 16.f);                // undo col duplication
        L += mxt;
        if (tid == 0) out[(size_t)b * MM + t] = L + __logf(S);
#pragma unroll
        for (int ti = 0; ti < 4; ++ti) emv[ti] = emn[ti];
        cur = nxt;
    }
}

extern "C" void kernel_launch(void* const* d_in, const int* in_sizes, int n_in,
                              void* d_out, int out_size, void* d_ws, size_t ws_size,
                              hipStream_t stream) {
    const int*   obs = (const int*)d_in[0];
    const float* pri = (const float*)d_in[1];
    const float* T   = (const float*)d_in[2];
    const float* E   = (const float*)d_in[3];
    float* out = (float*)d_out;
    char* ws = (char*)d_ws;

    float* c   = (float*)(ws + 0);
    float* lp  = (float*)(ws + 2048);
    float* M   = (float*)(ws + 4096);
    u32*   PA  = (u32*)(ws + 8192);                       // 256 KB fp8 A-frags
    float* EtT = (float*)(ws + 8192 + 256 * 1024);        // 512 KB

    k_col_lse<<<8,   64, 0, stream>>>(T, c);
    k_priors <<<1,  512, 0, stream>>>(pri, lp);
    k_rowM   <<<512, 64, 0, stream>>>(T, c, M);
    k_packA  <<<512, 64, 0, stream>>>(T, c, M, PA);
    k_rowE   <<<512, 64, 0, stream>>>(E, EtT);
    k_scan   <<<BB, 512, 0, stream>>>(obs, lp, M, PA, EtT, out);
}